// Round 7
// baseline (278.071 us; speedup 1.0000x reference)
//
#include <hip/hip_runtime.h>

#define THRESH 0.05f

typedef __attribute__((ext_vector_type(4)))  int   int32x4;
typedef __attribute__((ext_vector_type(16))) int   int32x16;
typedef __attribute__((ext_vector_type(4)))  float floatx4;

// ---------------------------------------------------------------------------
// Kernel 1: quantize weight [1024,1024] fp32 -> int8 {-1,0,+1} in FRAGMENT
// ORDER for the mfma_i32_32x32x32_i8 B-operand:
//   1 KB block per (nb,k):  wqf[((nb*32 + k)*64 + lane)*16 + byte]
//   lane l supplies w[col = nb*32 + (l&31)][k*32 + (l>>5)*16 .. +16)
// (unchanged -- verified absmax 0 in rounds 0/1/3/4/5/6.)
// ---------------------------------------------------------------------------
__global__ __launch_bounds__(256) void quant_w_kernel(const float* __restrict__ w,
                                                      signed char* __restrict__ wqf) {
    int c = blockIdx.x * 256 + threadIdx.x;   // 16-byte chunk id, 0..65535
    int l  = c & 63;
    int k  = (c >> 6) & 31;
    int nb = c >> 11;
    int col   = nb * 32 + (l & 31);
    int kbase = k * 32 + (l >> 5) * 16;
    const float* src = w + col * 1024 + kbase;
    signed char q[16];
    #pragma unroll
    for (int j = 0; j < 4; ++j) {
        float4 f = *(const float4*)(src + j * 4);
        q[j * 4 + 0] = (signed char)((f.x >= THRESH) - (f.x <= -THRESH));
        q[j * 4 + 1] = (signed char)((f.y >= THRESH) - (f.y <= -THRESH));
        q[j * 4 + 2] = (signed char)((f.z >= THRESH) - (f.z <= -THRESH));
        q[j * 4 + 3] = (signed char)((f.w >= THRESH) - (f.w <= -THRESH));
    }
    *(int32x4*)(wqf + (size_t)c * 16) = *(const int32x4*)q;
}

// ---------------------------------------------------------------------------
// Kernel 2: 32-row slab ternary GEMM, 32x32x32 i8 MFMA, OCCUPANCY-FIRST.
// Block = 512 threads (8 waves) x 32-row slab; 32 KB LDS; grid 1024 ->
// 4 blocks/CU, 32 waves/CU (100%) under __launch_bounds__(512, 8)
// (64-VGPR cap; est. use ~54: 16 acc + 16 b + 4 af + addr).
// vs round 5 (92.5 us): no resource saturated (MFMA 33K, LDS 49K, HBM
// 104K, L2-B 37K cyc/CU vs 222K wall) and per-wave serial work ~20K cyc
// -> the wall is CONCURRENCY: 16 waves all barrier-locked in one phase
// cadence (HBM idle in compute, LDS idle in staging) + grid 512 = 2.0
// blocks/CU exact -> placement skew tail (measured occ 31% < 50% cap).
// Fix: 2x waves/CU, 4 desynced blocks/CU, finer-grain load balance.
// Cost accepted: B L2 traffic 0.5 -> 1 GB (~30 us aggregate, overlapped).
// vs round 6 (100.5 us REGRESSED): ping-pong + per-4-load fences + cross-ot
// liveness = mild spill (WRITE 141 MB) -> rejected; inner loop stays
// round-5-shaped: single-buffered burst + ONE sched_barrier per burst.
// Kept: fragment-order conflict-free LDS (1 KB block per k, slot =
// lane^(k&7)), unswapped epilogue (WRITE = ideal 131 MB).
// ---------------------------------------------------------------------------
__global__ __launch_bounds__(512, 8) void tern_gemm_kernel(const float* __restrict__ x,
                                                           const signed char* __restrict__ wqf,
                                                           float* __restrict__ out) {
    __shared__ __attribute__((aligned(16))) signed char a_lds[32 * 1024];
    const int tid = threadIdx.x;
    const long rowbase = (long)blockIdx.x * 32;

    // ---- Phase 1: stage + quantize x slab (32 rows x 1024 K) into
    //      fragment-order LDS. chunk c: row = c>>6 (0..31), cir = c&63;
    //      k = cir>>1, hi = cir&1 ->
    //      addr = k*1024 + ((hi*32 + row) ^ (k&7))*16
    //      (read side: lane reads slot lane^(k&7) -> hi=lane>>5, row=lane&31)
    #pragma unroll
    for (int i = 0; i < 4; ++i) {
        int c   = tid + i * 512;   // chunk id 0..2047
        int row = c >> 6;          // 64 chunks per row
        int cir = c & 63;          // chunk-in-row
        const floatx4* src = (const floatx4*)(x + (rowbase + row) * 1024 + cir * 16);
        signed char q[16];
        #pragma unroll
        for (int j = 0; j < 4; ++j) {
            floatx4 f = __builtin_nontemporal_load(src + j);
            #pragma unroll
            for (int e = 0; e < 4; ++e)
                q[j * 4 + e] = (signed char)((f[e] >= THRESH) - (f[e] <= -THRESH));
        }
        int k    = cir >> 1;
        int slot = ((cir & 1) * 32 + row) ^ (k & 7);
        *(int32x4*)(a_lds + k * 1024 + slot * 16) = *(const int32x4*)q;
    }
    __syncthreads();

    // ---- Phase 2: compute. Wave owns ONE 32-col tile per ot (4 ot). ----
    const int wave = tid >> 6;    // 0..7
    const int lane = tid & 63;
    const int l31  = lane & 31;
    const int hi   = lane >> 5;

    for (int ot = 0; ot < 4; ++ot) {
        const int nb = ot * 8 + wave;        // this wave's 32-col tile
        const signed char* bp = wqf + (size_t)nb * 32768 + lane * 16;

        int32x16 acc = {0,0,0,0,0,0,0,0,0,0,0,0,0,0,0,0};   // 32 rows x 32 cols

        // 8 bursts of 4 K-steps. Single-buffered b[4] (16 VGPR), one
        // sched_barrier per burst (round-5 proven shape): clean kill
        // points, bounded pressure, no spill.
        #pragma unroll
        for (int ks = 0; ks < 8; ++ks) {
            int32x4 b[4];
            #pragma unroll
            for (int j = 0; j < 4; ++j)
                b[j] = *(const int32x4*)(bp + (size_t)(ks * 4 + j) * 1024);
            __builtin_amdgcn_sched_barrier(0);
            #pragma unroll
            for (int j = 0; j < 4; ++j) {
                const int k  = ks * 4 + j;
                const int sl = (lane ^ (k & 7)) * 16;
                int32x4 af = *(const int32x4*)(a_lds + k * 1024 + sl);
                acc = __builtin_amdgcn_mfma_i32_32x32x32_i8(af, b[j], acc, 0, 0, 0);
            }
        }

        // ---- epilogue: scalar nt stores; per instr 64 lanes cover two
        //      contiguous 128 B row segments (rows rit(hi=0), rit(hi=1)) ----
        const int cb = nb * 32 + l31;
        #pragma unroll
        for (int r = 0; r < 16; ++r) {
            const int rit = (r & 3) + 8 * (r >> 2) + 4 * hi;   // 0..31
            __builtin_nontemporal_store((float)acc[r],
                                        out + (rowbase + rit) * 1024 + cb);
        }
    }
}

extern "C" void kernel_launch(void* const* d_in, const int* in_sizes, int n_in,
                              void* d_out, int out_size, void* d_ws, size_t ws_size,
                              hipStream_t stream) {
    const float* x = (const float*)d_in[0];      // [32768, 1024] fp32
    const float* w = (const float*)d_in[1];      // [1024, 1024] fp32
    float* out = (float*)d_out;                  // [32768, 1024] fp32
    signed char* wqf = (signed char*)d_ws;       // 1 MB int8 scratch (fragment order)

    quant_w_kernel<<<dim3(256), dim3(256), 0, stream>>>(w, wqf);
    // 32768 rows / 32 = 1024 blocks (4 per CU), 8 waves each, 32 waves/CU
    tern_gemm_kernel<<<dim3(1024), dim3(512), 0, stream>>>(x, wqf, out);
}

// Round 8
// 270.279 us; speedup vs baseline: 1.0288x; 1.0288x over previous
//
#include <hip/hip_runtime.h>

#define THRESH 0.05f

typedef __attribute__((ext_vector_type(4)))  int   int32x4;
typedef __attribute__((ext_vector_type(16))) int   int32x16;
typedef __attribute__((ext_vector_type(4)))  float floatx4;

// ---------------------------------------------------------------------------
// Kernel 1: quantize weight [1024,1024] fp32 -> int8 {-1,0,+1} in FRAGMENT
// ORDER for the mfma_i32_32x32x32_i8 B-operand:
//   1 KB block per (nb,k):  wqf[((nb*32 + k)*64 + lane)*16 + byte]
//   lane l supplies w[col = nb*32 + (l&31)][k*32 + (l>>5)*16 .. +16)
// (unchanged -- verified absmax 0 in rounds 0..7.)
// ---------------------------------------------------------------------------
__global__ __launch_bounds__(256) void quant_w_kernel(const float* __restrict__ w,
                                                      signed char* __restrict__ wqf) {
    int c = blockIdx.x * 256 + threadIdx.x;   // 16-byte chunk id, 0..65535
    int l  = c & 63;
    int k  = (c >> 6) & 31;
    int nb = c >> 11;
    int col   = nb * 32 + (l & 31);
    int kbase = k * 32 + (l >> 5) * 16;
    const float* src = w + col * 1024 + kbase;
    signed char q[16];
    #pragma unroll
    for (int j = 0; j < 4; ++j) {
        float4 f = *(const float4*)(src + j * 4);
        q[j * 4 + 0] = (signed char)((f.x >= THRESH) - (f.x <= -THRESH));
        q[j * 4 + 1] = (signed char)((f.y >= THRESH) - (f.y <= -THRESH));
        q[j * 4 + 2] = (signed char)((f.z >= THRESH) - (f.z <= -THRESH));
        q[j * 4 + 3] = (signed char)((f.w >= THRESH) - (f.w <= -THRESH));
    }
    *(int32x4*)(wqf + (size_t)c * 16) = *(const int32x4*)q;
}

// ---------------------------------------------------------------------------
// Kernel 1b: quantize x [32768,1024] fp32 -> int8 fragment order (32 MB).
// Same fragment layout as wqf but over rows: 1 KB block per (mb,k):
//   xq[((mb*32 + k)*64 + l)*16]  holds  x[mb*32 + (l&31)][k*32 + (l>>5)*16..)
// Writes perfectly coalesced (wave = one 1 KB block); reads are 64 B/thread
// contiguous segments (quant_w-proven pattern). Pure streaming, ~167 MB.
// ---------------------------------------------------------------------------
__global__ __launch_bounds__(256) void quant_x_kernel(const float* __restrict__ x,
                                                      signed char* __restrict__ xq) {
    int c = blockIdx.x * 256 + threadIdx.x;   // chunk id, 0..2097151
    int l  = c & 63;
    int k  = (c >> 6) & 31;
    int mb = c >> 11;                          // 0..1023
    long row  = (long)mb * 32 + (l & 31);
    int kbase = k * 32 + (l >> 5) * 16;
    const float* src = x + row * 1024 + kbase;
    signed char q[16];
    #pragma unroll
    for (int j = 0; j < 4; ++j) {
        float4 f = *(const float4*)(src + j * 4);
        q[j * 4 + 0] = (signed char)((f.x >= THRESH) - (f.x <= -THRESH));
        q[j * 4 + 1] = (signed char)((f.y >= THRESH) - (f.y <= -THRESH));
        q[j * 4 + 2] = (signed char)((f.z >= THRESH) - (f.z <= -THRESH));
        q[j * 4 + 3] = (signed char)((f.w >= THRESH) - (f.w <= -THRESH));
    }
    *(int32x4*)(xq + (size_t)c * 16) = *(const int32x4*)q;
}

// ---------------------------------------------------------------------------
// Kernel 2 (v2): K-CHUNKED streaming ternary GEMM, 32x32x32 i8 MFMA.
// Block = 512 threads (8 waves) = 64 rows x 256 cols; each wave owns ONE
// 32-col tile -> acc (32 regs) persists across K, enabling K-chunking.
// K in 8 chunks of 128; LDS = 2 x 8 KB double buffer (16 KB).
// Per chunk per wave: 4 B-loads + 1 next-chunk x-load issued EARLY (T14),
// 8 ds_read + 8 MFMA on current buffer, ds_write next chunk LATE, 1 barrier.
// WHY (R7 post-mortem): all prior variants were bulk-synchronous -- every
// block staged x in one HBM-bound phase (MFMA idle), then computed (HBM
// ~30%); identical-duration blocks launched together never desync, so the
// phases never overlap. Occupancy 31->59% (R7) changed nothing. Here
// staging is spread through the kernel in 1 KB/wave/chunk pieces and x is
// pre-quantized int8 (4x fewer staged bytes, zero quantize VALU in GEMM;
// xq 33 MB is L3-resident so the 4 col-sibling blocks refetch from cache).
// Regs: 32 acc + 16 b + 4 xn + 8 af + ~12 addr ~= 72 << 128 cap of
// (512,4) -- no spill (R3/R4/R6 lesson: traffic tripwire on FETCH/WRITE).
// ---------------------------------------------------------------------------
__global__ __launch_bounds__(512, 4) void tern_gemm_v2(const signed char* __restrict__ xq,
                                                       const signed char* __restrict__ wqf,
                                                       float* __restrict__ out) {
    __shared__ __attribute__((aligned(16))) signed char a_lds[2][8192];
    const int tid  = threadIdx.x;
    const int wv   = tid >> 6;          // 0..7
    const int lane = tid & 63;
    const int l31  = lane & 31;
    const int hi   = lane >> 5;

    const int rb = blockIdx.x >> 2;     // 0..511  row-slab (64 rows)
    const int cb = blockIdx.x & 3;      // 0..3    col-group (256 cols)
    const long rowbase = (long)rb * 64;

    // staging role: wave wv stages LDS block (kloc = wv>>1, mbloc = wv&1)
    const int mbloc = wv & 1;           // which 32-row half of the slab
    const int kloc  = wv >> 1;          // which of 4 k-steps in the chunk
    const int mb    = rb * 2 + mbloc;
    // chunk c source: xq[((mb*32 + 4c + kloc)*64 + lane)*16] = base + c*4096
    const signed char* xsrc = xq + ((size_t)(mb * 32 + kloc) * 64 + lane) * 16;
    signed char* ldst = &a_lds[0][0] + (kloc * 2 + mbloc) * 1024 + lane * 16;

    const int nb = cb * 8 + wv;         // this wave's 32-col tile
    const signed char* bp = wqf + (size_t)nb * 32768 + lane * 16;

    int32x16 acc0 = {0,0,0,0,0,0,0,0,0,0,0,0,0,0,0,0};  // rows  0..31
    int32x16 acc1 = acc0;                                 // rows 32..63

    // prologue: stage chunk 0 into buffer 0
    {
        int32x4 x0 = *(const int32x4*)xsrc;
        *(int32x4*)ldst = x0;
    }
    __syncthreads();

    #pragma unroll
    for (int c = 0; c < 8; ++c) {
        const int bi = c & 1;
        const signed char* lb = &a_lds[bi][0];

        // B burst for this chunk + next x chunk, all issued before compute
        int32x4 b0 = *(const int32x4*)(bp + (size_t)(c * 4 + 0) * 1024);
        int32x4 b1 = *(const int32x4*)(bp + (size_t)(c * 4 + 1) * 1024);
        int32x4 b2 = *(const int32x4*)(bp + (size_t)(c * 4 + 2) * 1024);
        int32x4 b3 = *(const int32x4*)(bp + (size_t)(c * 4 + 3) * 1024);
        int32x4 xn = {0, 0, 0, 0};
        if (c < 7) xn = *(const int32x4*)(xsrc + (size_t)(c + 1) * 4096);
        __builtin_amdgcn_sched_barrier(0);

        // 8 ds_read + 8 MFMA on the ready buffer (2 dependent chains)
        #pragma unroll
        for (int j = 0; j < 4; ++j) {
            const int32x4 bj = (j == 0) ? b0 : (j == 1) ? b1 : (j == 2) ? b2 : b3;
            int32x4 af0 = *(const int32x4*)(lb + (j * 2 + 0) * 1024 + lane * 16);
            int32x4 af1 = *(const int32x4*)(lb + (j * 2 + 1) * 1024 + lane * 16);
            acc0 = __builtin_amdgcn_mfma_i32_32x32x32_i8(af0, bj, acc0, 0, 0, 0);
            acc1 = __builtin_amdgcn_mfma_i32_32x32x32_i8(af1, bj, acc1, 0, 0, 0);
        }

        // write-late: next chunk into the other buffer, then one barrier
        if (c < 7) *(int32x4*)(ldst + (bi ^ 1) * 8192) = xn;
        __syncthreads();
    }

    // epilogue: scalar nt stores; per instr 64 lanes = two 128 B segments
    const int ccol = nb * 32 + l31;
    #pragma unroll
    for (int r = 0; r < 16; ++r) {
        const int rit = (r & 3) + 8 * (r >> 2) + 4 * hi;
        float* o0 = out + (rowbase + rit) * 1024 + ccol;     // rows  0..31
        float* o1 = o0 + 32L * 1024;                         // rows 32..63
        __builtin_nontemporal_store((float)acc0[r], o0);
        __builtin_nontemporal_store((float)acc1[r], o1);
    }
}

// ---------------------------------------------------------------------------
// Fallback GEMM (round 5 verbatim, 92.5 us proven): used if ws_size < 33 MB.
// ---------------------------------------------------------------------------
__global__ __launch_bounds__(512, 4) void tern_gemm_fb(const float* __restrict__ x,
                                                       const signed char* __restrict__ wqf,
                                                       float* __restrict__ out) {
    __shared__ __attribute__((aligned(16))) signed char a_lds[64 * 1024];
    const int tid = threadIdx.x;
    const long rowbase = (long)blockIdx.x * 64;

    #pragma unroll
    for (int i = 0; i < 8; ++i) {
        int c   = tid + i * 512;
        int row = c >> 6;
        int cir = c & 63;
        const floatx4* src = (const floatx4*)(x + (rowbase + row) * 1024 + cir * 16);
        signed char q[16];
        #pragma unroll
        for (int j = 0; j < 4; ++j) {
            floatx4 f = __builtin_nontemporal_load(src + j);
            #pragma unroll
            for (int e = 0; e < 4; ++e)
                q[j * 4 + e] = (signed char)((f[e] >= THRESH) - (f[e] <= -THRESH));
        }
        int k    = cir >> 1;
        int blk  = k * 2 + (row >> 5);
        int slot = ((cir & 1) * 32 + (row & 31)) ^ (k & 7);
        *(int32x4*)(a_lds + blk * 1024 + slot * 16) = *(const int32x4*)q;
    }
    __syncthreads();

    const int wave = tid >> 6;
    const int lane = tid & 63;
    const int l31  = lane & 31;
    const int hi   = lane >> 5;

    for (int ot = 0; ot < 4; ++ot) {
        const int nb = ot * 8 + wave;
        const signed char* bp = wqf + (size_t)nb * 32768 + lane * 16;

        int32x16 acc0 = {0,0,0,0,0,0,0,0,0,0,0,0,0,0,0,0};
        int32x16 acc1 = acc0;

        #pragma unroll
        for (int ks = 0; ks < 4; ++ks) {
            int32x4 b[8];
            #pragma unroll
            for (int j = 0; j < 8; ++j)
                b[j] = *(const int32x4*)(bp + (size_t)(ks * 8 + j) * 1024);
            __builtin_amdgcn_sched_barrier(0);
            #pragma unroll
            for (int j = 0; j < 8; ++j) {
                const int k  = ks * 8 + j;
                const int sl = (lane ^ (k & 7)) * 16;
                int32x4 af0 = *(const int32x4*)(a_lds + (k * 2 + 0) * 1024 + sl);
                int32x4 af1 = *(const int32x4*)(a_lds + (k * 2 + 1) * 1024 + sl);
                acc0 = __builtin_amdgcn_mfma_i32_32x32x32_i8(af0, b[j], acc0, 0, 0, 0);
                acc1 = __builtin_amdgcn_mfma_i32_32x32x32_i8(af1, b[j], acc1, 0, 0, 0);
            }
        }

        const int cbcol = nb * 32 + l31;
        #pragma unroll
        for (int r = 0; r < 16; ++r) {
            const int rit = (r & 3) + 8 * (r >> 2) + 4 * hi;
            float* o0 = out + (rowbase + rit) * 1024 + cbcol;
            float* o1 = o0 + 32L * 1024;
            __builtin_nontemporal_store((float)acc0[r], o0);
            __builtin_nontemporal_store((float)acc1[r], o1);
        }
    }
}

extern "C" void kernel_launch(void* const* d_in, const int* in_sizes, int n_in,
                              void* d_out, int out_size, void* d_ws, size_t ws_size,
                              hipStream_t stream) {
    const float* x = (const float*)d_in[0];      // [32768, 1024] fp32
    const float* w = (const float*)d_in[1];      // [1024, 1024] fp32
    float* out = (float*)d_out;                  // [32768, 1024] fp32
    signed char* wqf = (signed char*)d_ws;                    // 1 MB
    signed char* xq  = (signed char*)d_ws + (1u << 20);       // 32 MB

    quant_w_kernel<<<dim3(256), dim3(256), 0, stream>>>(w, wqf);

    if (ws_size >= 33ull * 1024 * 1024) {
        quant_x_kernel<<<dim3(8192), dim3(256), 0, stream>>>(x, xq);
        // 512 row-slabs x 4 col-groups = 2048 blocks, 8 waves each
        tern_gemm_v2<<<dim3(2048), dim3(512), 0, stream>>>(xq, wqf, out);
    } else {
        tern_gemm_fb<<<dim3(512), dim3(512), 0, stream>>>(x, wqf, out);
    }
}